// Round 5
// baseline (3107.263 us; speedup 1.0000x reference)
//
#include <hip/hip_runtime.h>

// Encoder: 2-layer LSTM (H1=64, H2=32, IN=2), B=512, T=4096, + FC [32->16].
// R5: R4 + forced weight register-residency. R4's VGPR_Count=96 (<128 weight
// floats) proved the scheduler's occupancy-driven rematerialization was still
// sinking the invariant weight loads into the loop (re-streaming from L1 every
// step). Two locks:
//   (a) amdgpu_waves_per_eu(2,2): max occupancy = what we actually run, so the
//       remat-for-occupancy heuristic has no objective;
//   (b) empty inline-asm "+v" pins on all 32 weight float4s: asm defs cannot
//       be rematerialized, so the values are forced live across the loop.
// Roles: waves 2,3 = layer 1 (2 gate-rows/lane); waves 0,1 = layer 2 (1 full
// 96-wide row/lane), one step behind; single barrier per step.

#define TT 4096
#define BB 512

typedef float f4 __attribute__((ext_vector_type(4)));

__device__ __forceinline__ float fexp2(float x){ return __builtin_amdgcn_exp2f(x); }
__device__ __forceinline__ float frcp (float x){ return __builtin_amdgcn_rcpf(x); }
__device__ __forceinline__ float sigm (float x){ return frcp(1.0f + fexp2(x * -1.4426950408889634f)); }
__device__ __forceinline__ float tanh_(float x){ return 1.0f - 2.0f * frcp(1.0f + fexp2(x * 2.8853900817779268f)); }

__device__ __forceinline__ float rlane(float v, int lane){
  return __builtin_bit_cast(float, __builtin_amdgcn_readlane(__builtin_bit_cast(int, v), lane));
}
template<int CTRL>
__device__ __forceinline__ float qperm(float v){
  const int s = __builtin_bit_cast(int, v);
  return __builtin_bit_cast(float, __builtin_amdgcn_update_dpp(s, s, CTRL, 0xF, 0xF, true));
}

#define PIN8(a,b,c,d,e,f,g,h) \
  asm volatile("" : "+v"(a), "+v"(b), "+v"(c), "+v"(d), \
                    "+v"(e), "+v"(f), "+v"(g), "+v"(h))

extern "C" __global__
__attribute__((amdgpu_flat_work_group_size(256, 256), amdgpu_waves_per_eu(2, 2)))
void lstm_enc_kernel(
    const float* __restrict__ x,
    const float* __restrict__ Wih1, const float* __restrict__ Whh1,
    const float* __restrict__ bih1, const float* __restrict__ bhh1,
    const float* __restrict__ Wih2, const float* __restrict__ Whh2,
    const float* __restrict__ bih2, const float* __restrict__ bhh2,
    const float* __restrict__ Wfc,  const float* __restrict__ bfc,
    float* __restrict__ out)
{
    const int tid = threadIdx.x;
    const int l   = tid & 63;
    // wave id as a PROVABLY SCALAR value -> s_cbranch on isL1, not exec-masking
    const int wv  = __builtin_amdgcn_readfirstlane(tid >> 6);
    const bool isL1 = (wv >= 2);
    const int b   = blockIdx.x;

    __shared__ float h1s[2][64];
    __shared__ float h2s[2][32];

    // ---- role indices ----
    const int j1  = (wv & 1) * 32 + (l >> 1);   // L1 unit (waves 2,3)
    const int gp  = l & 1;                      // 0: rows(i,f)  1: rows(g,o)
    const int rA1 = (2 * gp) * 64 + j1;
    const int rB1 = rA1 + 64;

    const int u2   = (wv & 1) * 16 + (l >> 2);  // L2 unit (waves 0,1)
    const int g2   = l & 3;                     // gate class
    const int row2 = g2 * 32 + u2;

    const int rA_s = isL1 ? rA1 : 0;
    const int rB_s = isL1 ? rB1 : 0;
    const int r2_s = isL1 ? 0   : row2;

    // ---- weight base pointers (address select; loads unconditional) ----
    const f4* pA  = (const f4*)(isL1 ? (Whh1 + rA1 * 64)      : (Wih2 + row2 * 64));
    const f4* pB1 = (const f4*)(isL1 ? (Whh1 + rB1 * 64)      : (Whh2 + row2 * 32));
    const f4* pB2 = (const f4*)(isL1 ? (Whh1 + rB1 * 64 + 32) : (Whh2 + row2 * 32));

    // ---- 32 named f4 = 128 weight VGPRs ----
    f4 wA0 = pA[0],  wA1 = pA[1],  wA2 = pA[2],   wA3 = pA[3];
    f4 wA4 = pA[4],  wA5 = pA[5],  wA6 = pA[6],   wA7 = pA[7];
    f4 wA8 = pA[8],  wA9 = pA[9],  wA10 = pA[10], wA11 = pA[11];
    f4 wA12 = pA[12], wA13 = pA[13], wA14 = pA[14], wA15 = pA[15];
    f4 wB0 = pB1[0], wB1 = pB1[1], wB2 = pB1[2],  wB3 = pB1[3];
    f4 wB4 = pB1[4], wB5 = pB1[5], wB6 = pB1[6],  wB7 = pB1[7];
    f4 wB8 = pB2[0], wB9 = pB2[1], wB10 = pB2[2], wB11 = pB2[3];
    f4 wB12 = pB2[4], wB13 = pB2[5], wB14 = pB2[6], wB15 = pB2[7];

    // hard-pin: asm defs are not rematerializable -> live across the loop
    PIN8(wA0, wA1, wA2,  wA3,  wA4,  wA5,  wA6,  wA7);
    PIN8(wA8, wA9, wA10, wA11, wA12, wA13, wA14, wA15);
    PIN8(wB0, wB1, wB2,  wB3,  wB4,  wB5,  wB6,  wB7);
    PIN8(wB8, wB9, wB10, wB11, wB12, wB13, wB14, wB15);

    const float bbA = isL1 ? (bih1[rA_s] + bhh1[rA_s]) : (bih2[r2_s] + bhh2[r2_s]);
    const float bbB = bih1[rB_s] + bhh1[rB_s];
    const float wxA0 = Wih1[rA_s * 2 + 0], wxA1 = Wih1[rA_s * 2 + 1];
    const float wxB0 = Wih1[rB_s * 2 + 0], wxB1 = Wih1[rB_s * 2 + 1];

    const float gpf = (float)gp;                    // L1 activation blend
    const float g2t = (g2 == 2) ? 1.0f : 0.0f;      // L2 activation blend

    const float* xb = x + (size_t)b * (TT * 2);
    float2 vx = make_float2(0.f, 0.f), vxn = make_float2(0.f, 0.f);
    if (isL1) vxn = ((const float2*)xb)[l];         // chunk 0

    if (tid < 64) h1s[0][tid] = 0.0f;
    if (tid < 32) { h2s[0][tid] = 0.0f; h2s[1][tid] = 0.0f; }
    __syncthreads();

    float cc1 = 0.0f, cc2 = 0.0f;

#define L1K(K) { \
    const float s0 = rlane(vh1.x, K); \
    const float s1 = rlane(vh1.y, K); \
    const float s2 = rlane(vh1.z, K); \
    const float s3 = rlane(vh1.w, K); \
    aA0 = fmaf(wA##K.x, s0, aA0); aB0 = fmaf(wB##K.x, s0, aB0); \
    aA1 = fmaf(wA##K.y, s1, aA1); aB1 = fmaf(wB##K.y, s1, aB1); \
    aA2 = fmaf(wA##K.z, s2, aA2); aB2 = fmaf(wB##K.z, s2, aB2); \
    aA3 = fmaf(wA##K.w, s3, aA3); aB3 = fmaf(wB##K.w, s3, aB3); }

#define L2A(K) { \
    a0 = fmaf(wA##K.x, rlane(vh1.x, K), a0); \
    a1 = fmaf(wA##K.y, rlane(vh1.y, K), a1); \
    a2 = fmaf(wA##K.z, rlane(vh1.z, K), a2); \
    a3 = fmaf(wA##K.w, rlane(vh1.w, K), a3); }

#define L2B(K) { \
    a0 = fmaf(wB##K.x, rlane(vh2.x, K), a0); \
    a1 = fmaf(wB##K.y, rlane(vh2.y, K), a1); \
    a2 = fmaf(wB##K.z, rlane(vh2.z, K), a2); \
    a3 = fmaf(wB##K.w, rlane(vh2.w, K), a3); }

    // t in [0, TT]: L1 computes step t (t<TT); L2 computes step t-1 (t>0).
    for (int t = 0; t <= TT; ++t) {
        const int rb = t & 1;
        const int wb = rb ^ 1;

        // h1(t-1), lane-distributed: lane m in [0,16) holds h1[4m..4m+3]
        const f4 vh1 = ((const f4*)h1s[rb])[l & 15];

        if (isL1) {
            if (t < TT) {
                if ((t & 63) == 0) {
                    vx = vxn;
                    if (t + 64 < TT) vxn = ((const float2*)xb)[(t >> 6) * 64 + 64 + l];
                }
                const float x0 = rlane(vx.x, t & 63);
                const float x1 = rlane(vx.y, t & 63);

                float aA0=0.f,aA1=0.f,aA2=0.f,aA3=0.f;
                float aB0=0.f,aB1=0.f,aB2=0.f,aB3=0.f;
                L1K(0)  L1K(1)  L1K(2)  L1K(3)  L1K(4)  L1K(5)  L1K(6)  L1K(7)
                L1K(8)  L1K(9)  L1K(10) L1K(11) L1K(12) L1K(13) L1K(14) L1K(15)
                const float preA = ((aA0+aA1)+(aA2+aA3)) + fmaf(wxA0, x0, fmaf(wxA1, x1, bbA));
                const float preB = ((aB0+aB1)+(aB2+aB3)) + fmaf(wxB0, x0, fmaf(wxB1, x1, bbB));

                // actA: sigm (gp=0, i-row) or tanh (gp=1, g-row), branchless:
                // tanh(x) = 2*sigm(2x) - 1
                const float pa   = fmaf(gpf, preA, preA);       // x or 2x
                const float sa   = sigm(pa);
                const float actA = fmaf(gpf, sa - 1.0f, sa);    // s or 2s-1
                const float actB = sigm(preB);                  // f-row / o-row

                const float pA_ = qperm<0xB1>(actA);            // pair swap
                const float pB_ = qperm<0xB1>(actB);
                const float gi = gp ? pA_  : actA;
                const float gf = gp ? pB_  : actB;
                const float gg = gp ? actA : pA_;
                const float go = gp ? actB : pB_;
                cc1 = fmaf(gf, cc1, gi * gg);
                const float h1v = go * tanh_(cc1);
                if (gp == 0) h1s[wb][j1] = h1v;
            }
        } else if (t > 0) {
            // layer 2, step t-1: h2(t-2) lane-distributed (lane m<8: h2[4m..4m+3])
            const f4 vh2 = ((const f4*)h2s[rb])[l & 7];
            float a0=0.f,a1=0.f,a2=0.f,a3=0.f;
            L2A(0)  L2A(1)  L2A(2)  L2A(3)  L2A(4)  L2A(5)  L2A(6)  L2A(7)
            L2A(8)  L2A(9)  L2A(10) L2A(11) L2A(12) L2A(13) L2A(14) L2A(15)
            L2B(0)  L2B(1)  L2B(2)  L2B(3)  L2B(4)  L2B(5)  L2B(6)  L2B(7)
            const float pre2 = bbA + ((a0+a1)+(a2+a3));

            const float p2   = fmaf(g2t, pre2, pre2);
            const float s2v  = sigm(p2);
            const float act2 = fmaf(g2t, s2v - 1.0f, s2v);

            const float i2 = qperm<0x00>(act2);
            const float f2 = qperm<0x55>(act2);
            const float g2v= qperm<0xAA>(act2);
            const float o2 = qperm<0xFF>(act2);
            cc2 = fmaf(f2, cc2, i2 * g2v);
            const float h2v = o2 * tanh_(cc2);
            if (g2 == 0) h2s[wb][u2] = h2v;
        }
        __syncthreads();
    }

    // Loop ran through t=TT: h2(TT-1) was written to h2s[1].
    if (tid < 16) {
        float s = bfc[tid];
        const float* wr = Wfc + tid * 32;
        #pragma unroll
        for (int k = 0; k < 32; ++k) s = fmaf(wr[k], h2s[1][k], s);
        out[b * 16 + tid] = s;
    }
#undef L1K
#undef L2A
#undef L2B
}

extern "C" void kernel_launch(void* const* d_in, const int* in_sizes, int n_in,
                              void* d_out, int out_size, void* d_ws, size_t ws_size,
                              hipStream_t stream) {
    const float* x    = (const float*)d_in[0];
    const float* Wih1 = (const float*)d_in[1];
    const float* Whh1 = (const float*)d_in[2];
    const float* bih1 = (const float*)d_in[3];
    const float* bhh1 = (const float*)d_in[4];
    const float* Wih2 = (const float*)d_in[5];
    const float* Whh2 = (const float*)d_in[6];
    const float* bih2 = (const float*)d_in[7];
    const float* bhh2 = (const float*)d_in[8];
    const float* Wfc  = (const float*)d_in[9];
    const float* bfc  = (const float*)d_in[10];

    hipLaunchKernelGGL(lstm_enc_kernel, dim3(BB), dim3(256), 0, stream,
        x, Wih1, Whh1, bih1, bhh1, Wih2, Whh2, bih2, bhh2, Wfc, bfc,
        (float*)d_out);
}